// Round 1
// baseline (384.189 us; speedup 1.0000x reference)
//
#include <hip/hip_runtime.h>
#include <stdint.h>
#include <stddef.h>

#define NEG 0.1f

typedef __attribute__((ext_vector_type(8))) short short8;
typedef __attribute__((ext_vector_type(16))) float floatx16;

__device__ __forceinline__ unsigned f2bf(float f) {
  union { float f; unsigned u; } v; v.f = f;
  unsigned r = v.u + 0x7FFFu + ((v.u >> 16) & 1u);   // RNE
  return r >> 16;
}
__device__ __forceinline__ float lrelu(float x) { return fmaxf(x, NEG * x); }

// ---------------- transpose x (L,B,E) -> xt (B,L,E) : row permutation, rows contiguous
__global__ void k_transpose_x(const float* __restrict__ x, float* __restrict__ xt) {
  int r = blockIdx.x;              // out row = b*100 + l
  int b = r / 100, l = r - b * 100;
  const float4* src = (const float4*)(x + (size_t)(l * 32 + b) * 512);
  float4* dst = (float4*)(xt + (size_t)r * 512);
  dst[threadIdx.x] = src[threadIdx.x];   // 128 threads * 16B = 2KB row
}

// ---------------- conv weight prep: Wt[f][ks*E + e] = cw[f][e][ks], bf16
__global__ void k_wtconv(const float* __restrict__ cw, unsigned short* __restrict__ wt, int E) {
  int idx = blockIdx.x * 256 + threadIdx.x;   // over F*E
  if (idx >= 256 * E) return;
  int f = idx / E, e = idx - f * E;
  const float* s = cw + (size_t)idx * 3;
  unsigned short* d = wt + (size_t)f * 3 * E + e;
  d[0] = (unsigned short)f2bf(s[0]);
  d[E] = (unsigned short)f2bf(s[1]);
  d[2 * E] = (unsigned short)f2bf(s[2]);
}

// ---------------- Wab prep: Wab_t[n][kp] (n<128: Wa col n; n>=128: Wb col n-128), K padded 258->320
__global__ void k_wab(const float* __restrict__ W1, unsigned short* __restrict__ wab) {
  int idx = blockIdx.x * 256 + threadIdx.x;   // 256*320
  int n = idx / 320, kp = idx - n * 320;
  float v = 0.f;
  if (kp < 258) {
    int d = (n < 128) ? kp : (258 + kp);
    v = W1[(size_t)d * 128 + (n & 127)];
  }
  wab[idx] = (unsigned short)f2bf(v);
}

// ---------------- MLP weight prep: wt[z][n][k] = Wz[k*128+n] bf16 (B-frag wants W^T rows)
__global__ void k_wmlp(const float* __restrict__ W2, const float* __restrict__ W3,
                       const float* __restrict__ W4, unsigned short* __restrict__ wt) {
  int z = blockIdx.y;
  const float* W = (z == 0) ? W2 : ((z == 1) ? W3 : W4);
  int idx = blockIdx.x * 256 + threadIdx.x;   // 16384
  int n = idx >> 7, k = idx & 127;
  wt[(size_t)z * 16384 + idx] = (unsigned short)f2bf(W[k * 128 + n]);
}

// ---------------- hc[b][m] = h[b] @ Wc + b1  (Wc = W1 rows 516..1027)
__global__ void k_hwc(const float* __restrict__ h, const float* __restrict__ W1,
                      const float* __restrict__ b1, float* __restrict__ hc) {
  int b = blockIdx.x, m = threadIdx.x;   // 128 threads
  const float* hr = h + b * 512;
  float acc = b1[m];
  for (int k = 0; k < 512; ++k) acc += hr[k] * W1[(size_t)(516 + k) * 128 + m];
  hc[b * 128 + m] = acc;
}

// ---------------- im2col layer1: I[r][ks*512+e] = xt[b][l+ks-1][e] (zero pad), bf16
__global__ void k_im2col1(const float* __restrict__ xt, unsigned short* __restrict__ I) {
  int idx = blockIdx.x * 256 + threadIdx.x;     // r*192 + seg
  int r = idx / 192, seg = idx - r * 192;
  int b = r / 100, l = r - b * 100;
  int k = seg * 8, ks = k >> 9, e = k & 511;
  int lp = l + ks - 1;
  uint4 val;
  if (lp < 0 || lp >= 100) { val.x = val.y = val.z = val.w = 0u; }
  else {
    const float* s = xt + ((size_t)(b * 100 + lp) * 512 + e);
    float4 f0 = *(const float4*)(s);
    float4 f1 = *(const float4*)(s + 4);
    val.x = f2bf(f0.x) | (f2bf(f0.y) << 16);
    val.y = f2bf(f0.z) | (f2bf(f0.w) << 16);
    val.z = f2bf(f1.x) | (f2bf(f1.y) << 16);
    val.w = f2bf(f1.z) | (f2bf(f1.w) << 16);
  }
  *(uint4*)(I + (size_t)idx * 8) = val;
}

// ---------------- im2col + BN-apply (layers 2..4 input): z is post-lrelu conv out (b,l,256)
__global__ void k_im2col_bn(const float* __restrict__ z, const float* __restrict__ bs,
                            const float* __restrict__ gam, const float* __restrict__ bet,
                            unsigned short* __restrict__ I) {
  int idx = blockIdx.x * 256 + threadIdx.x;     // r*96 + seg
  int r = idx / 96, seg = idx - r * 96;
  int b = r / 100, l = r - b * 100;
  int k = seg * 8, ks = k >> 8, e = k & 255;
  int lp = l + ks - 1;
  unsigned o[8];
  if (lp < 0 || lp >= 100) {
    for (int i = 0; i < 8; ++i) o[i] = 0;
  } else {
    const float* s = z + ((size_t)(b * 100 + lp) * 256 + e);
    const float inv = 1.f / 3200.f;
    for (int i = 0; i < 8; ++i) {
      float m = bs[e + i] * inv;
      float var = bs[256 + e + i] * inv - m * m;
      float sc = gam[e + i] * rsqrtf(var + 1e-5f);
      float sh = bet[e + i] - m * sc;
      o[i] = f2bf(s[i] * sc + sh);
    }
  }
  uint4 val;
  val.x = o[0] | (o[1] << 16); val.y = o[2] | (o[3] << 16);
  val.z = o[4] | (o[5] << 16); val.w = o[6] | (o[7] << 16);
  *(uint4*)(I + (size_t)idx * 8) = val;
}

// ---------------- xf build: BN-apply layer4 + coords, K padded 258->320, bf16
__global__ void k_prepxf(const float* __restrict__ z, const float* __restrict__ bs,
                         const float* __restrict__ gam, const float* __restrict__ bet,
                         unsigned short* __restrict__ xfb) {
  int idx = blockIdx.x * 256 + threadIdx.x;    // r*40 + seg
  int r = idx / 40, seg = idx - r * 40;
  int l = r % 100;
  int k = seg * 8;
  unsigned o[8];
  if (k < 256) {
    const float* s = z + ((size_t)r * 256 + k);
    const float inv = 1.f / 3200.f;
    for (int i = 0; i < 8; ++i) {
      float m = bs[k + i] * inv;
      float var = bs[256 + k + i] * inv - m * m;
      float sc = gam[k + i] * rsqrtf(var + 1e-5f);
      float sh = bet[k + i] - m * sc;
      o[i] = f2bf(s[i] * sc + sh);
    }
  } else {
    for (int i = 0; i < 8; ++i) o[i] = 0;
    if (k == 256) {
      o[0] = f2bf(((float)l * 0.1f - 2.0f) * 0.5f);
      o[1] = f2bf(((float)(l % 10) - 2.0f) * 0.5f);
    }
  }
  uint4 val;
  val.x = o[0] | (o[1] << 16); val.y = o[2] | (o[3] << 16);
  val.z = o[4] | (o[5] << 16); val.w = o[6] | (o[7] << 16);
  *(uint4*)(xfb + (size_t)idx * 8) = val;
}

// ---------------- conv GEMM: Y = I(3200xK) @ Wt^T -> z(b,l,f) = lrelu(Y+cb); atomic BN sums
// block = 64 rows x 64 cols, 4 waves of 32x32; K-chunks of 64 staged in LDS
__global__ __launch_bounds__(256) void k_convgemm(
    const unsigned short* __restrict__ G, const unsigned short* __restrict__ Wt, int K,
    const float* __restrict__ cb, float* __restrict__ z, float* __restrict__ bsum) {
  __shared__ unsigned short Gs[64 * 72];
  __shared__ unsigned short Ws[64 * 72];
  int tid = threadIdx.x;
  int lane = tid & 63, wave = tid >> 6;
  int rt = blockIdx.x, ct = blockIdx.y;
  int rh = wave & 1, ch = wave >> 1;
  floatx16 acc;
#pragma unroll
  for (int i = 0; i < 16; ++i) acc[i] = 0.f;
  int row_s = tid >> 3, seg = tid & 7;
  int mrow = lane & 31;
  int koff = (lane >> 5) << 3;
  for (int kc = 0; kc < K; kc += 64) {
#pragma unroll
    for (int it = 0; it < 2; ++it) {
      int rr = row_s + it * 32;
      *(uint4*)(&Gs[rr * 72 + seg * 8]) = *(const uint4*)(G + ((size_t)(rt * 64 + rr) * K + kc + seg * 8));
      *(uint4*)(&Ws[rr * 72 + seg * 8]) = *(const uint4*)(Wt + ((size_t)(ct * 64 + rr) * K + kc + seg * 8));
    }
    __syncthreads();
#pragma unroll
    for (int kk = 0; kk < 4; ++kk) {
      short8 a = *(const short8*)(&Gs[(rh * 32 + mrow) * 72 + kk * 16 + koff]);
      short8 w8 = *(const short8*)(&Ws[(ch * 32 + mrow) * 72 + kk * 16 + koff]);
      acc = __builtin_amdgcn_mfma_f32_32x32x16_bf16(a, w8, acc, 0, 0, 0);
    }
    __syncthreads();
  }
  int f = ct * 64 + ch * 32 + mrow;
  float bias = cb[f];
  float s1 = 0.f, s2 = 0.f;
#pragma unroll
  for (int reg = 0; reg < 16; ++reg) {
    int rowp = (reg & 3) + 8 * (reg >> 2) + 4 * (lane >> 5);  // verified C/D layout
    int row = rt * 64 + rh * 32 + rowp;
    float v = acc[reg] + bias;
    v = fmaxf(v, NEG * v);
    z[(size_t)row * 256 + f] = v;
    s1 += v; s2 += v * v;
  }
  s1 += __shfl_xor(s1, 32, 64);
  s2 += __shfl_xor(s2, 32, 64);
  if (lane < 32) { atomicAdd(&bsum[f], s1); atomicAdd(&bsum[256 + f], s2); }
}

// ---------------- A/C GEMM: [A|C] = xfb(3200x320) @ Wab^T; C gets +hc[b]
__global__ __launch_bounds__(256) void k_acgemm(
    const unsigned short* __restrict__ G, const unsigned short* __restrict__ Wt, int K,
    const float* __restrict__ hc, float* __restrict__ A, float* __restrict__ C) {
  __shared__ unsigned short Gs[64 * 72];
  __shared__ unsigned short Ws[64 * 72];
  int tid = threadIdx.x;
  int lane = tid & 63, wave = tid >> 6;
  int rt = blockIdx.x, ct = blockIdx.y;
  int rh = wave & 1, ch = wave >> 1;
  floatx16 acc;
#pragma unroll
  for (int i = 0; i < 16; ++i) acc[i] = 0.f;
  int row_s = tid >> 3, seg = tid & 7;
  int mrow = lane & 31;
  int koff = (lane >> 5) << 3;
  for (int kc = 0; kc < K; kc += 64) {
#pragma unroll
    for (int it = 0; it < 2; ++it) {
      int rr = row_s + it * 32;
      *(uint4*)(&Gs[rr * 72 + seg * 8]) = *(const uint4*)(G + ((size_t)(rt * 64 + rr) * K + kc + seg * 8));
      *(uint4*)(&Ws[rr * 72 + seg * 8]) = *(const uint4*)(Wt + ((size_t)(ct * 64 + rr) * K + kc + seg * 8));
    }
    __syncthreads();
#pragma unroll
    for (int kk = 0; kk < 4; ++kk) {
      short8 a = *(const short8*)(&Gs[(rh * 32 + mrow) * 72 + kk * 16 + koff]);
      short8 w8 = *(const short8*)(&Ws[(ch * 32 + mrow) * 72 + kk * 16 + koff]);
      acc = __builtin_amdgcn_mfma_f32_32x32x16_bf16(a, w8, acc, 0, 0, 0);
    }
    __syncthreads();
  }
  int n = ct * 64 + ch * 32 + mrow;
#pragma unroll
  for (int reg = 0; reg < 16; ++reg) {
    int rowp = (reg & 3) + 8 * (reg >> 2) + 4 * (lane >> 5);
    int row = rt * 64 + rh * 32 + rowp;
    float v = acc[reg];
    if (n < 128) A[(size_t)row * 128 + n] = v;
    else {
      int b = row / 100;
      C[(size_t)row * 128 + (n - 128)] = v + hc[b * 128 + (n - 128)];
    }
  }
}

// ---------------- fused relation MLP: g0=lrelu(C_i+A_j) -> 3x(GEMM128+bias+lrelu) -> sum(i,j)
// block = 128 rows(pairs) x 128 feat, 4 waves x 32 rows; W2/3/4 + g resident in LDS
__global__ __launch_bounds__(256, 1) void k_mlp(
    const float* __restrict__ Ab, const float* __restrict__ Cb,
    const unsigned short* __restrict__ Wt, const float* __restrict__ b2,
    const float* __restrict__ b3, const float* __restrict__ b4, float* __restrict__ sout) {
  extern __shared__ unsigned short sm[];       // [3*128*136 W][128*136 gs][3*128 f32 bias][128 f32 sblk]
  unsigned short* gs = sm + 3 * 17408;
  float* biasl = (float*)(sm + 4 * 17408);
  float* sblk = biasl + 384;
  int tid = threadIdx.x;
  int lane = tid & 63, wave = tid >> 6;
  int b = blockIdx.y, tile = blockIdx.x;

  for (int i = tid; i < 6144; i += 256) {      // stage 3x128x128 bf16 weights (pad stride 136)
    int w = i >> 11, rem = i & 2047, row = rem >> 4, sg = rem & 15;
    *(uint4*)(&sm[w * 17408 + row * 136 + sg * 8]) =
        *(const uint4*)(Wt + ((size_t)w * 16384 + row * 128 + sg * 8));
  }
  if (tid < 128) {
    biasl[tid] = b2[tid]; biasl[128 + tid] = b3[tid]; biasl[256 + tid] = b4[tid];
    sblk[tid] = 0.f;
  }
  int wb = wave * 32;
  {  // g0 build: 2 lanes per row, 64 cols each
    int lr = wb + (lane >> 1);
    int hh = lane & 1;
    int r = tile * 128 + lr;
    if (r > 9999) r = 9999;                    // clamp; masked at final sum
    const float* Crow = Cb + (size_t)(b * 100 + r / 100) * 128;
    const float* Arow = Ab + (size_t)(b * 100 + r % 100) * 128;
#pragma unroll
    for (int it = 0; it < 16; ++it) {
      int col = hh * 64 + it * 4;
      float4 c4 = *(const float4*)(Crow + col);
      float4 a4 = *(const float4*)(Arow + col);
      float v0 = c4.x + a4.x; v0 = fmaxf(v0, NEG * v0);
      float v1 = c4.y + a4.y; v1 = fmaxf(v1, NEG * v1);
      float v2 = c4.z + a4.z; v2 = fmaxf(v2, NEG * v2);
      float v3 = c4.w + a4.w; v3 = fmaxf(v3, NEG * v3);
      uint2 p;
      p.x = f2bf(v0) | (f2bf(v1) << 16);
      p.y = f2bf(v2) | (f2bf(v3) << 16);
      *(uint2*)(&gs[lr * 136 + col]) = p;
    }
  }
  __syncthreads();

  int mrow = wb + (lane & 31);
  int koff = (lane >> 5) << 3;
  for (int layer = 0; layer < 3; ++layer) {
    const unsigned short* W = sm + layer * 17408;
    const float* bia = biasl + (layer << 7);
    floatx16 acc[4];
#pragma unroll
    for (int nt = 0; nt < 4; ++nt)
#pragma unroll
      for (int i = 0; i < 16; ++i) acc[nt][i] = 0.f;
#pragma unroll
    for (int kk = 0; kk < 8; ++kk) {
      short8 a = *(const short8*)(&gs[mrow * 136 + kk * 16 + koff]);
#pragma unroll
      for (int nt = 0; nt < 4; ++nt) {
        short8 w8 = *(const short8*)(&W[(nt * 32 + (lane & 31)) * 136 + kk * 16 + koff]);
        acc[nt] = __builtin_amdgcn_mfma_f32_32x32x16_bf16(a, w8, acc[nt], 0, 0, 0);
      }
    }
    __syncthreads();                            // all waves done reading gs
    if (layer < 2) {
#pragma unroll
      for (int nt = 0; nt < 4; ++nt) {
        int col = nt * 32 + (lane & 31);
        float bv = bia[col];
#pragma unroll
        for (int reg = 0; reg < 16; ++reg) {
          int rowp = (reg & 3) + 8 * (reg >> 2) + 4 * (lane >> 5);
          float v = acc[nt][reg] + bv;
          v = fmaxf(v, NEG * v);
          gs[(wb + rowp) * 136 + col] = (unsigned short)f2bf(v);
        }
      }
    } else {
#pragma unroll
      for (int nt = 0; nt < 4; ++nt) {
        int col = nt * 32 + (lane & 31);
        float bv = bia[col];
        float cs = 0.f;
#pragma unroll
        for (int reg = 0; reg < 16; ++reg) {
          int rowp = (reg & 3) + 8 * (reg >> 2) + 4 * (lane >> 5);
          int r = tile * 128 + wb + rowp;
          float v = acc[nt][reg] + bv;
          v = fmaxf(v, NEG * v);
          cs += (r < 10000) ? v : 0.f;          // mask padded rows
        }
        cs += __shfl_xor(cs, 32, 64);
        if (lane < 32) atomicAdd(&sblk[col], cs);
      }
    }
    __syncthreads();
  }
  if (tid < 128) atomicAdd(&sout[(b << 7) + tid], sblk[tid]);
}

// ---------------- final: out = lrelu(lrelu(s@F1+fb1)@F2+fb2), one block per b
__global__ void k_final(const float* __restrict__ s, const float* __restrict__ F1,
                        const float* __restrict__ fb1, const float* __restrict__ F2,
                        const float* __restrict__ fb2, float* __restrict__ out) {
  __shared__ float sl[128], t1[128];
  int b = blockIdx.x, t = threadIdx.x;
  if (t < 128) sl[t] = s[b * 128 + t];
  __syncthreads();
  if (t < 128) {
    float a = fb1[t];
    for (int k = 0; k < 128; ++k) a += sl[k] * F1[k * 128 + t];
    t1[t] = fmaxf(a, NEG * a);
  }
  __syncthreads();
  for (int o = t; o < 512; o += 256) {
    float a = fb2[o];
    for (int k = 0; k < 128; ++k) a += t1[k] * F2[k * 512 + o];
    out[b * 512 + o] = fmaxf(a, NEG * a);
  }
}

extern "C" void kernel_launch(void* const* d_in, const int* in_sizes, int n_in,
                              void* d_out, int out_size, void* d_ws, size_t ws_size,
                              hipStream_t stream) {
  const float* x   = (const float*)d_in[0];
  const float* h   = (const float*)d_in[1];
  const float* cw1 = (const float*)d_in[2];
  const float* cb1 = (const float*)d_in[3];
  const float* g1  = (const float*)d_in[4];
  const float* be1 = (const float*)d_in[5];
  const float* cw2 = (const float*)d_in[6];
  const float* cb2 = (const float*)d_in[7];
  const float* g2  = (const float*)d_in[8];
  const float* be2 = (const float*)d_in[9];
  const float* cw3 = (const float*)d_in[10];
  const float* cb3 = (const float*)d_in[11];
  const float* g3  = (const float*)d_in[12];
  const float* be3 = (const float*)d_in[13];
  const float* cw4 = (const float*)d_in[14];
  const float* cb4 = (const float*)d_in[15];
  const float* g4  = (const float*)d_in[16];
  const float* be4 = (const float*)d_in[17];
  const float* W1  = (const float*)d_in[18];
  const float* b1  = (const float*)d_in[19];
  const float* W2  = (const float*)d_in[20];
  const float* b2  = (const float*)d_in[21];
  const float* W3  = (const float*)d_in[22];
  const float* b3  = (const float*)d_in[23];
  const float* W4  = (const float*)d_in[24];
  const float* b4  = (const float*)d_in[25];
  const float* F1  = (const float*)d_in[26];
  const float* fb1 = (const float*)d_in[27];
  const float* F2  = (const float*)d_in[28];
  const float* fb2 = (const float*)d_in[29];

  char* ws = (char*)d_ws;
  float* bn0  = (float*)(ws + 0);
  float* bn1  = (float*)(ws + 2048);
  float* bn2  = (float*)(ws + 4096);
  float* bn3  = (float*)(ws + 6144);
  float* sbuf = (float*)(ws + 8192);
  float* xt   = (float*)(ws + 24576);
  float* za   = (float*)(ws + 6578176);
  float* zb   = (float*)(ws + 9854976);
  unsigned short* I    = (unsigned short*)(ws + 13131776);
  unsigned short* wt1  = (unsigned short*)(ws + 22962176);
  unsigned short* wt2  = (unsigned short*)(ws + 23748608);
  unsigned short* wt3  = (unsigned short*)(ws + 24141824);
  unsigned short* wt4  = (unsigned short*)(ws + 24535040);
  unsigned short* wab  = (unsigned short*)(ws + 24928256);
  unsigned short* wmlp = (unsigned short*)(ws + 25092096);
  unsigned short* xfb  = (unsigned short*)(ws + 25190400);
  float* Abuf = (float*)(ws + 27238400);
  float* Cbuf = (float*)(ws + 28876800);
  float* hc   = (float*)(ws + 30515200);
  // total ws use: 30531584 bytes (~29.1 MB)

  hipMemsetAsync(d_ws, 0, 24576, stream);     // bn sums + s accumulator

  k_transpose_x<<<3200, 128, 0, stream>>>(x, xt);
  k_wtconv<<<512, 256, 0, stream>>>(cw1, wt1, 512);
  k_wtconv<<<256, 256, 0, stream>>>(cw2, wt2, 256);
  k_wtconv<<<256, 256, 0, stream>>>(cw3, wt3, 256);
  k_wtconv<<<256, 256, 0, stream>>>(cw4, wt4, 256);
  k_wab<<<320, 256, 0, stream>>>(W1, wab);
  k_wmlp<<<dim3(64, 3), 256, 0, stream>>>(W2, W3, W4, wmlp);
  k_hwc<<<32, 128, 0, stream>>>(h, W1, b1, hc);

  k_im2col1<<<2400, 256, 0, stream>>>(xt, I);
  k_convgemm<<<dim3(50, 4), 256, 0, stream>>>(I, wt1, 1536, cb1, za, bn0);
  k_im2col_bn<<<1200, 256, 0, stream>>>(za, bn0, g1, be1, I);
  k_convgemm<<<dim3(50, 4), 256, 0, stream>>>(I, wt2, 768, cb2, zb, bn1);
  k_im2col_bn<<<1200, 256, 0, stream>>>(zb, bn1, g2, be2, I);
  k_convgemm<<<dim3(50, 4), 256, 0, stream>>>(I, wt3, 768, cb3, za, bn2);
  k_im2col_bn<<<1200, 256, 0, stream>>>(za, bn2, g3, be3, I);
  k_convgemm<<<dim3(50, 4), 256, 0, stream>>>(I, wt4, 768, cb4, zb, bn3);
  k_prepxf<<<500, 256, 0, stream>>>(zb, bn3, g4, be4, xfb);
  k_acgemm<<<dim3(50, 4), 256, 0, stream>>>(xfb, wab, 320, hc, Abuf, Cbuf);

  hipFuncSetAttribute((const void*)k_mlp, hipFuncAttributeMaxDynamicSharedMemorySize, 141312);
  k_mlp<<<dim3(79, 32), 256, 141312, stream>>>(Abuf, Cbuf, wmlp, b2, b3, b4, sbuf);
  k_final<<<32, 256, 0, stream>>>(sbuf, F1, fb1, F2, fb2, (float*)d_out);
}